// Round 3
// baseline (115.479 us; speedup 1.0000x reference)
//
#include <hip/hip_runtime.h>

#define TPB 256
#define NW  (TPB / 64)

__device__ __forceinline__ float pair_loss(float p0, float s0, float p1, float s1) {
    float dp = p0 - p1;
    float ds = s0 - s1;
    float sg = (ds > 0.0f) ? 1.0f : ((ds < 0.0f) ? -1.0f : 0.0f);
    float t  = dp * sg;
    // stable softplus(-t) = max(-t,0) + log1p(exp(-|t|))
    return fmaxf(-t, 0.0f) + log1pf(__expf(-fabsf(t)));
}

// Compute row's top softmax prob p and mask (argmax==0) from 16 logits.
__device__ __forceinline__ void row_stats(const float* __restrict__ outp, int row,
                                          float& p, bool& mask) {
    const float4* o4 = (const float4*)outp + (size_t)row * 4;
    float4 a = o4[0];
    float4 b = o4[1];
    float4 c = o4[2];
    float4 d = o4[3];
    float m01 = fmaxf(fmaxf(a.x, a.y), fmaxf(a.z, a.w));
    float m23 = fmaxf(fmaxf(b.x, b.y), fmaxf(b.z, b.w));
    float m45 = fmaxf(fmaxf(c.x, c.y), fmaxf(c.z, c.w));
    float m67 = fmaxf(fmaxf(d.x, d.y), fmaxf(d.z, d.w));
    float m = fmaxf(fmaxf(m01, m23), fmaxf(m45, m67));
    float sum = __expf(a.x - m) + __expf(a.y - m) + __expf(a.z - m) + __expf(a.w - m)
              + __expf(b.x - m) + __expf(b.y - m) + __expf(b.z - m) + __expf(b.w - m)
              + __expf(c.x - m) + __expf(c.y - m) + __expf(c.z - m) + __expf(c.w - m)
              + __expf(d.x - m) + __expf(d.y - m) + __expf(d.z - m) + __expf(d.w - m);
    p = 1.0f / sum;
    mask = (a.x == m);
}

// Single fused kernel: block-local adjacent-selected pairs + own cross-boundary
// pair via forward scan into following rows; one atomicAdd per block.
__global__ void k_fused(const float* __restrict__ outp,
                        const float* __restrict__ score,
                        float* __restrict__ out, int B) {
    __shared__ float sp[TPB];
    __shared__ float ss[TPB];
    __shared__ unsigned long long wmask[NW];
    __shared__ float wsum[NW];

    int row  = blockIdx.x * TPB + threadIdx.x;
    int lane = threadIdx.x & 63;
    int wid  = threadIdx.x >> 6;

    bool mask = false;
    float p = 0.0f, s = 0.0f;
    if (row < B) {
        row_stats(outp, row, p, mask);
        s = score[row];                // coalesced
    }
    sp[threadIdx.x] = p;
    ss[threadIdx.x] = s;

    unsigned long long bal = __ballot(mask);
    if (lane == 0) wmask[wid] = bal;
    __syncthreads();

    float acc = 0.0f;
    if (mask) {
        // next selected thread index within this block
        unsigned long long above = bal & ~((2ull << lane) - 1ull); // lane 63: 2ull<<63 wraps to 0 -> above=0
        int nxt = -1;
        if (above) {
            nxt = (wid << 6) + __ffsll(above) - 1;
        } else {
            for (int w = wid + 1; w < NW; ++w) {
                if (wmask[w]) { nxt = (w << 6) + __ffsll(wmask[w]) - 1; break; }
            }
        }
        if (nxt >= 0) acc = pair_loss(p, s, sp[nxt], ss[nxt]);
    }

    // wave 0: forward scan for the block's cross-boundary pair
    if (wid == 0) {
        // locate last selected row in this block
        int last = -1;
        for (int w = NW - 1; w >= 0; --w) {
            if (wmask[w]) { last = (w << 6) + 63 - __clzll(wmask[w]); break; }
        }
        if (last >= 0) {
            float pl = sp[last];
            float sl = ss[last];
            int base = (blockIdx.x + 1) * TPB;
            while (base < B) {
                int r = base + lane;
                bool sel = false;
                float pf = 0.0f, sf = 0.0f;
                if (r < B) {
                    row_stats(outp, r, pf, sel);
                    sf = score[r];
                }
                unsigned long long b2 = __ballot(sel);
                if (b2) {
                    int fl = __ffsll(b2) - 1;
                    float pfirst = __shfl(pf, fl);
                    float sfirst = __shfl(sf, fl);
                    if (lane == 0) acc += pair_loss(pl, sl, pfirst, sfirst);
                    break;
                }
                base += 64;
            }
        }
    }

    // block reduce acc -> one atomicAdd
    for (int off = 32; off > 0; off >>= 1) acc += __shfl_down(acc, off);
    if (lane == 0) wsum[wid] = acc;
    __syncthreads();
    if (threadIdx.x == 0) {
        atomicAdd(out, wsum[0] + wsum[1] + wsum[2] + wsum[3]);
    }
}

extern "C" void kernel_launch(void* const* d_in, const int* in_sizes, int n_in,
                              void* d_out, int out_size, void* d_ws, size_t ws_size,
                              hipStream_t stream) {
    const float* outp  = (const float*)d_in[0];   // [B,16] logits
    const float* score = (const float*)d_in[1];   // [B]
    float* out = (float*)d_out;

    int B  = in_sizes[1];
    int nb = (B + TPB - 1) / TPB;

    hipMemsetAsync(out, 0, sizeof(float), stream);
    k_fused<<<nb, TPB, 0, stream>>>(outp, score, out, B);
}

// Round 4
// 36.074 us; speedup vs baseline: 3.2012x; 3.2012x over previous
//
#include <hip/hip_runtime.h>

#define TPB 256
#define NW  (TPB / 64)

__device__ __forceinline__ float pair_loss(float p0, float s0, float p1, float s1) {
    float dp = p0 - p1;
    float ds = s0 - s1;
    float sg = (ds > 0.0f) ? 1.0f : ((ds < 0.0f) ? -1.0f : 0.0f);
    float t  = dp * sg;
    // stable softplus(-t) = max(-t,0) + log1p(exp(-|t|))
    return fmaxf(-t, 0.0f) + log1pf(__expf(-fabsf(t)));
}

// Compute row's top softmax prob p and mask (argmax==0) from 16 logits.
__device__ __forceinline__ void row_stats(const float* __restrict__ outp, int row,
                                          float& p, bool& mask) {
    const float4* o4 = (const float4*)outp + (size_t)row * 4;
    float4 a = o4[0];
    float4 b = o4[1];
    float4 c = o4[2];
    float4 d = o4[3];
    float m01 = fmaxf(fmaxf(a.x, a.y), fmaxf(a.z, a.w));
    float m23 = fmaxf(fmaxf(b.x, b.y), fmaxf(b.z, b.w));
    float m45 = fmaxf(fmaxf(c.x, c.y), fmaxf(c.z, c.w));
    float m67 = fmaxf(fmaxf(d.x, d.y), fmaxf(d.z, d.w));
    float m = fmaxf(fmaxf(m01, m23), fmaxf(m45, m67));
    float sum = __expf(a.x - m) + __expf(a.y - m) + __expf(a.z - m) + __expf(a.w - m)
              + __expf(b.x - m) + __expf(b.y - m) + __expf(b.z - m) + __expf(b.w - m)
              + __expf(c.x - m) + __expf(c.y - m) + __expf(c.z - m) + __expf(c.w - m)
              + __expf(d.x - m) + __expf(d.y - m) + __expf(d.z - m) + __expf(d.w - m);
    p = 1.0f / sum;
    mask = (a.x == m);
}

// k1: block-local adjacent-selected pairs + own cross-boundary pair via
// forward scan; contention-free per-block partial write (no atomics).
__global__ void k_fused(const float* __restrict__ outp,
                        const float* __restrict__ score,
                        float* __restrict__ bpart, int B) {
    __shared__ float sp[TPB];
    __shared__ float ss[TPB];
    __shared__ unsigned long long wmask[NW];
    __shared__ float wsum[NW];

    int row  = blockIdx.x * TPB + threadIdx.x;
    int lane = threadIdx.x & 63;
    int wid  = threadIdx.x >> 6;

    bool mask = false;
    float p = 0.0f, s = 0.0f;
    if (row < B) {
        row_stats(outp, row, p, mask);
        s = score[row];                // coalesced
    }
    sp[threadIdx.x] = p;
    ss[threadIdx.x] = s;

    unsigned long long bal = __ballot(mask);
    if (lane == 0) wmask[wid] = bal;
    __syncthreads();

    float acc = 0.0f;
    if (mask) {
        // next selected thread index within this block
        unsigned long long above = bal & ~((2ull << lane) - 1ull); // lane 63: 2ull<<63 wraps to 0
        int nxt = -1;
        if (above) {
            nxt = (wid << 6) + __ffsll(above) - 1;
        } else {
            for (int w = wid + 1; w < NW; ++w) {
                if (wmask[w]) { nxt = (w << 6) + __ffsll(wmask[w]) - 1; break; }
            }
        }
        if (nxt >= 0) acc = pair_loss(p, s, sp[nxt], ss[nxt]);
    }

    // wave 0: forward scan for this block's cross-boundary pair
    if (wid == 0) {
        int last = -1;
        for (int w = NW - 1; w >= 0; --w) {
            if (wmask[w]) { last = (w << 6) + 63 - __clzll(wmask[w]); break; }
        }
        if (last >= 0) {
            float pl = sp[last];
            float sl = ss[last];
            int base = (blockIdx.x + 1) * TPB;
            while (base < B) {
                int r = base + lane;
                bool sel = false;
                float pf = 0.0f, sf = 0.0f;
                if (r < B) {
                    row_stats(outp, r, pf, sel);
                    sf = score[r];
                }
                unsigned long long b2 = __ballot(sel);
                if (b2) {
                    int fl = __ffsll(b2) - 1;
                    float pfirst = __shfl(pf, fl);
                    float sfirst = __shfl(sf, fl);
                    if (lane == 0) acc += pair_loss(pl, sl, pfirst, sfirst);
                    break;
                }
                base += 64;
            }
        }
    }

    // block reduce acc -> one contention-free write
    for (int off = 32; off > 0; off >>= 1) acc += __shfl_down(acc, off);
    if (lane == 0) wsum[wid] = acc;
    __syncthreads();
    if (threadIdx.x == 0) {
        bpart[blockIdx.x] = wsum[0] + wsum[1] + wsum[2] + wsum[3];
    }
}

// k2: single block sums the per-block partials, writes out[0] directly.
__global__ void k2_sum(const float* __restrict__ bpart, int nb,
                       float* __restrict__ out) {
    __shared__ float wsum[16];
    float acc = 0.0f;
    for (int b = threadIdx.x; b < nb; b += 1024) acc += bpart[b];
    int lane = threadIdx.x & 63;
    int wid  = threadIdx.x >> 6;
    for (int off = 32; off > 0; off >>= 1) acc += __shfl_down(acc, off);
    if (lane == 0) wsum[wid] = acc;
    __syncthreads();
    if (threadIdx.x == 0) {
        float t = 0.0f;
        for (int w = 0; w < 16; ++w) t += wsum[w];
        out[0] = t;
    }
}

extern "C" void kernel_launch(void* const* d_in, const int* in_sizes, int n_in,
                              void* d_out, int out_size, void* d_ws, size_t ws_size,
                              hipStream_t stream) {
    const float* outp  = (const float*)d_in[0];   // [B,16] logits
    const float* score = (const float*)d_in[1];   // [B]
    float* out = (float*)d_out;

    int B  = in_sizes[1];
    int nb = (B + TPB - 1) / TPB;

    float* bpart = (float*)d_ws;

    k_fused<<<nb, TPB, 0, stream>>>(outp, score, bpart, B);
    k2_sum<<<1, 1024, 0, stream>>>(bpart, nb, out);
}